// Round 7
// baseline (21.416 us; speedup 1.0000x reference)
//
#include <hip/hip_runtime.h>
#include <math.h>

#define LOG2E 1.4426950408889634f
#define LN2   0.6931471805599453f

typedef float v2f __attribute__((ext_vector_type(2)));

__device__ __forceinline__ float fast_exp2(float x) {
#if __has_builtin(__builtin_amdgcn_exp2f)
    return __builtin_amdgcn_exp2f(x);
#else
    return exp2f(x);
#endif
}

// ---------------------------------------------------------------------------
// Single fused kernel, register-resident coefficients, occupancy-tuned.
// Block = 512 threads (8 waves) handles 64 samples.
//   wave w: group g = w>>1 owns samples [g*16, g*16+16);
//           half  h = w&1  owns components [h*512, h*512+512).
//   Each lane holds 8 comps = 4 packed pairs (48 coef VGPRs). Target 6+
//   waves/SIMD via __launch_bounds__(512,6) (<=80 VGPRs).
// LDS: COEF[6][1024] (prep scratch) UNIONed with RED[64][132]+PART[64][9]
//   (reduce buffers) -> 35.3 KB/block, 4 blocks/CU possible.
// Hot loop per sample: 20 v_pk_fma + 8 v_exp + 8 v_add + 1 ds_write; samples
// are wave-uniform s_loads, #pragma unroll 4 batches them ahead.
// ---------------------------------------------------------------------------
__global__ __launch_bounds__(512, 6) void gm_fused(
        const float* __restrict__ sample,   // [N,2]
        const float* __restrict__ mu,       // [M,2]
        const float* __restrict__ A,        // [M,2,2]
        const float* __restrict__ w,        // [M,1]
        float* __restrict__ out) {          // [N,1]
    // ---- LDS union: prep-phase COEF overlaps reduce-phase RED/PART ----
    __shared__ __align__(16) char LBUF[36096];
    float (*COEF)[1024] = (float (*)[1024])LBUF;            // [6][1024] 24 KB
    float (*RED)[132]   = (float (*)[132])LBUF;             // [64][132] 33 KB
    float (*PART)[9]    = (float (*)[9])(LBUF + 64*132*4);  // [64][9]
    __shared__ float red8[8];

    const int tid  = threadIdx.x;
    const int lane = tid & 63;
    const int wid  = tid >> 6;              // 0..7

    // ================= Phase 1: coefficient prep ==========================
    const float2 wv = ((const float2*)w)[tid];      // comps 2t, 2t+1

    float v = fmaxf(wv.x, wv.y);
    #pragma unroll
    for (int o = 32; o; o >>= 1) v = fmaxf(v, __shfl_xor(v, o));
    if (lane == 0) red8[wid] = v;
    __syncthreads();
    float wmax = red8[0];
    #pragma unroll
    for (int k = 1; k < 8; k++) wmax = fmaxf(wmax, red8[k]);
    __syncthreads();

    v = expf(wv.x - wmax) + expf(wv.y - wmax);
    #pragma unroll
    for (int o = 32; o; o >>= 1) v += __shfl_xor(v, o);
    if (lane == 0) red8[wid] = v;
    __syncthreads();
    float sumew = 0.f;
    #pragma unroll
    for (int k = 0; k < 8; k++) sumew += red8[k];
    const float lse = wmax + logf(sumew);
    __syncthreads();                                 // red8 reused below

    float lw2[2], G00[2], G2[2], G11[2], MX[2], MY[2];
    const float wj[2] = {wv.x, wv.y};
    #pragma unroll
    for (int k = 0; k < 2; k++) {
        const int j = 2 * tid + k;
        const float4 a = ((const float4*)A)[j];
        const float g00 = 0.5f * (a.x*a.x + a.y*a.y);
        const float g01 = 0.5f * (a.x*a.z + a.y*a.w);
        const float g11 = 0.5f * (a.z*a.z + a.w*a.w);
        const float det = g00*g11 - g01*g01;
        lw2[k] = ((wj[k] - lse) + 0.5f * logf(det)) * LOG2E;
        G00[k] = g00 * LOG2E;
        G2[k]  = 2.f * g01 * LOG2E;
        G11[k] = g11 * LOG2E;
        const float2 m = ((const float2*)mu)[j];
        MX[k] = m.x; MY[k] = m.y;
    }

    v = fmaxf(lw2[0], lw2[1]);
    #pragma unroll
    for (int o = 32; o; o >>= 1) v = fmaxf(v, __shfl_xor(v, o));
    if (lane == 0) red8[wid] = v;
    __syncthreads();
    float Lmax = red8[0];
    #pragma unroll
    for (int k = 1; k < 8; k++) Lmax = fmaxf(Lmax, red8[k]);

    #pragma unroll
    for (int k = 0; k < 2; k++) {
        const int j = 2 * tid + k;
        const float mx = MX[k], my = MY[k];
        COEF[0][j] = lw2[k] - (G00[k]*mx*mx + G2[k]*mx*my + G11[k]*my*my) - Lmax;
        COEF[1][j] = 2.f*G00[k]*mx + G2[k]*my;
        COEF[2][j] = G2[k]*mx + 2.f*G11[k]*my;
        COEF[3][j] = -G00[k];
        COEF[4][j] = -G2[k];
        COEF[5][j] = -G11[k];
    }
    __syncthreads();

    // ========= Phase 2: 8 comps/lane -> 4 packed pairs in VGPRs ===========
    const int g = wid >> 1;                  // sample group 0..3
    const int h = wid & 1;                   // component half 0..1
    v2f C0[4], C1[4], C2[4], D0[4], D1[4], D2[4];
    #pragma unroll
    for (int k = 0; k < 4; k++) {
        const int j = h*512 + 128*k + lane;  // pair (j, j+64)
        C0[k] = (v2f){COEF[0][j], COEF[0][j+64]};
        C1[k] = (v2f){COEF[1][j], COEF[1][j+64]};
        C2[k] = (v2f){COEF[2][j], COEF[2][j+64]};
        D0[k] = (v2f){COEF[3][j], COEF[3][j+64]};
        D1[k] = (v2f){COEF[4][j], COEF[4][j+64]};
        D2[k] = (v2f){COEF[5][j], COEF[5][j+64]};
    }
    __syncthreads();   // ALL waves done reading COEF before RED overwrites it

    // ================= Phase 3: hot loop, 16 uniform samples ==============
    const int ls0 = g * 16;
    const int sbu = __builtin_amdgcn_readfirstlane(blockIdx.x * 64 + ls0);

    #pragma unroll 4
    for (int s = 0; s < 16; ++s) {
        const float2 xy = ((const float2*)sample)[sbu + s];    // s_load
        const v2f Xv = {xy.x, xy.x}, Yv = {xy.y, xy.y};

        v2f sv = {0.f, 0.f};
        #pragma unroll
        for (int k = 0; k < 4; k++) {
            // t = c0 + x*(c1 + d0*x + d1*y) + y*(c2 + d2*y)
            v2f i1 = __builtin_elementwise_fma(D0[k], Xv, C1[k]);
            i1     = __builtin_elementwise_fma(D1[k], Yv, i1);
            v2f i2 = __builtin_elementwise_fma(D2[k], Yv, C2[k]);
            v2f t  = __builtin_elementwise_fma(i1, Xv, C0[k]);
            t      = __builtin_elementwise_fma(i2, Yv, t);
            sv.x += fast_exp2(t.x);
            sv.y += fast_exp2(t.y);
        }
        RED[ls0 + s][h*64 + lane] = sv.x + sv.y;
    }
    __syncthreads();

    // ---- stage 1: 8 partials per sample (2-way LDS access, free) ----
    {
        const int r = tid >> 3, c = tid & 7;
        const float* row = &RED[r][c * 16];
        float p = 0.f;
        #pragma unroll
        for (int i = 0; i < 16; i++) p += row[i];
        PART[r][c] = p;
    }
    __syncthreads();

    // ---- stage 2: finish 64 samples ----
    if (tid < 64) {
        float st = 0.f;
        #pragma unroll
        for (int c = 0; c < 8; c++) st += PART[tid][c];
        const int si = blockIdx.x * 64 + tid;
        float ll;
        if (st >= 1e-30f) {
            ll = LN2 * (Lmax + log2f(st));
        } else {
            // Rare underflow: re-anchored two-pass over all M, recomputing
            // coefficients from global params (COEF LDS is gone by now).
            const float2 xy = ((const float2*)sample)[si];
            const float x = xy.x, y = xy.y;
            float m = -3e38f, ss = 0.f;
            for (int pass = 0; pass < 2; pass++) {
                float acc = -3e38f;
                if (pass) acc = 0.f;
                for (int j = 0; j < 1024; j++) {
                    const float4 a = ((const float4*)A)[j];
                    const float g00 = 0.5f * (a.x*a.x + a.y*a.y);
                    const float g01 = 0.5f * (a.x*a.z + a.y*a.w);
                    const float g11 = 0.5f * (a.z*a.z + a.w*a.w);
                    const float det = g00*g11 - g01*g01;
                    const float lw2j = ((w[j] - lse) + 0.5f * logf(det)) * LOG2E;
                    const float2 mm = ((const float2*)mu)[j];
                    const float dx = x - mm.x, dy = y - mm.y;
                    const float q = (g00*dx*dx + 2.f*g01*dx*dy + g11*dy*dy) * LOG2E;
                    const float t = lw2j - q - Lmax;
                    if (pass == 0) acc = fmaxf(acc, t);
                    else           acc += fast_exp2(t - m);
                }
                if (pass == 0) m = acc; else ss = acc;
            }
            ll = LN2 * (Lmax + m + log2f(ss));
        }
        out[si] = ll;
    }
}

extern "C" void kernel_launch(void* const* d_in, const int* in_sizes, int n_in,
                              void* d_out, int out_size, void* d_ws, size_t ws_size,
                              hipStream_t stream) {
    const float* sample = (const float*)d_in[0];   // [N,2]
    const float* mu     = (const float*)d_in[1];   // [M,2]
    const float* A      = (const float*)d_in[2];   // [M,2,2]
    const float* w      = (const float*)d_in[3];   // [M,1]
    float* out = (float*)d_out;

    const int N = in_sizes[0] / 2;                 // 65536
    // M fixed at 1024 (register/LDS layouts sized statically).

    gm_fused<<<N / 64, 512, 0, stream>>>(sample, mu, A, w, out);
}

// Round 8
// 19.234 us; speedup vs baseline: 1.1135x; 1.1135x over previous
//
#include <hip/hip_runtime.h>
#include <math.h>

#define LOG2E 1.4426950408889634f
#define LN2   0.6931471805599453f

typedef float v2f __attribute__((ext_vector_type(2)));

__device__ __forceinline__ float fast_exp2(float x) {
    return __builtin_amdgcn_exp2f(x);
}

// Guaranteed packed fp32 FMA (CDNA2+ VOP3P). The compiler does not reliably
// pack __builtin_elementwise_fma on v2f; this pins it.
__device__ __forceinline__ v2f pk_fma(v2f a, v2f b, v2f c) {
    v2f d;
    asm("v_pk_fma_f32 %0, %1, %2, %3" : "=v"(d) : "v"(a), "v"(b), "v"(c));
    return d;
}

// ---------------------------------------------------------------------------
// Single fused kernel, register-resident coefficients (R6 skeleton).
// Block = 512 threads (8 waves), 128 samples/block, 512 blocks (2/CU).
//  Phase 1: redundant per-block prep, log2 domain, Lmax anchor:
//           t_ij = c0 + c1 x + c2 y + d0 x^2 + d1 xy + d2 y^2 <= 0.
//           COEF2[c][p] holds coefficient c of components (2p, 2p+1) as v2f,
//           so phase-2 fragment loads are single ds_read_b64 (2-way, free).
//  Phase 2: each lane loads 16 comps = 8 packed pairs (96 coef VGPRs).
//  Phase 3: per wave, 16 wave-uniform samples (s_load); per sample
//           40 v_pk_fma (asm) + 16 v_exp + 16 v_add into FOUR accumulators
//           (4-deep chains), #pragma unroll 2 for cross-sample ILP to fill
//           trans-use hazard slots. One ds_write per sample.
//  Reduce: LDS transpose reduce (as R6), one log2 per sample.
// ---------------------------------------------------------------------------
__global__ __launch_bounds__(512, 4) void gm_fused(
        const float* __restrict__ sample,   // [N,2]
        const float* __restrict__ mu,       // [M,2]
        const float* __restrict__ A,        // [M,2,2]
        const float* __restrict__ w,        // [M,1]
        float* __restrict__ out) {          // [N,1]
    __shared__ v2f  COEF2[6][512];          // 24 KB
    __shared__ float RED[128][65];          // 33.3 KB
    __shared__ float PART[128][5];          // 2.6 KB
    __shared__ float red8[8];

    const int tid  = threadIdx.x;
    const int lane = tid & 63;
    const int wid  = tid >> 6;              // 0..7

    // ================= Phase 1: coefficient prep ==========================
    const float2 wv = ((const float2*)w)[tid];      // comps 2t, 2t+1

    float v = fmaxf(wv.x, wv.y);
    #pragma unroll
    for (int o = 32; o; o >>= 1) v = fmaxf(v, __shfl_xor(v, o));
    if (lane == 0) red8[wid] = v;
    __syncthreads();
    float wmax = red8[0];
    #pragma unroll
    for (int k = 1; k < 8; k++) wmax = fmaxf(wmax, red8[k]);
    __syncthreads();

    v = expf(wv.x - wmax) + expf(wv.y - wmax);
    #pragma unroll
    for (int o = 32; o; o >>= 1) v += __shfl_xor(v, o);
    if (lane == 0) red8[wid] = v;
    __syncthreads();
    float sumew = 0.f;
    #pragma unroll
    for (int k = 0; k < 8; k++) sumew += red8[k];
    const float lse = wmax + logf(sumew);
    __syncthreads();                                 // red8 reused below

    float lw2[2], G00[2], G2[2], G11[2], MX[2], MY[2];
    const float wj[2] = {wv.x, wv.y};
    #pragma unroll
    for (int k = 0; k < 2; k++) {
        const int j = 2 * tid + k;
        const float4 a = ((const float4*)A)[j];
        const float g00 = 0.5f * (a.x*a.x + a.y*a.y);
        const float g01 = 0.5f * (a.x*a.z + a.y*a.w);
        const float g11 = 0.5f * (a.z*a.z + a.w*a.w);
        const float det = g00*g11 - g01*g01;
        lw2[k] = ((wj[k] - lse) + 0.5f * logf(det)) * LOG2E;
        G00[k] = g00 * LOG2E;
        G2[k]  = 2.f * g01 * LOG2E;
        G11[k] = g11 * LOG2E;
        const float2 m = ((const float2*)mu)[j];
        MX[k] = m.x; MY[k] = m.y;
    }

    v = fmaxf(lw2[0], lw2[1]);
    #pragma unroll
    for (int o = 32; o; o >>= 1) v = fmaxf(v, __shfl_xor(v, o));
    if (lane == 0) red8[wid] = v;
    __syncthreads();
    float Lmax = red8[0];
    #pragma unroll
    for (int k = 1; k < 8; k++) Lmax = fmaxf(Lmax, red8[k]);

    {
        v2f c0v, c1v, c2v, d0v, d1v, d2v;
        #pragma unroll
        for (int k = 0; k < 2; k++) {
            const float mx = MX[k], my = MY[k];
            c0v[k] = lw2[k] - (G00[k]*mx*mx + G2[k]*mx*my + G11[k]*my*my) - Lmax;
            c1v[k] = 2.f*G00[k]*mx + G2[k]*my;
            c2v[k] = G2[k]*mx + 2.f*G11[k]*my;
            d0v[k] = -G00[k];
            d1v[k] = -G2[k];
            d2v[k] = -G11[k];
        }
        COEF2[0][tid] = c0v;  COEF2[1][tid] = c1v;  COEF2[2][tid] = c2v;
        COEF2[3][tid] = d0v;  COEF2[4][tid] = d1v;  COEF2[5][tid] = d2v;
    }
    __syncthreads();

    // ========= Phase 2: 16 comps/lane -> 8 packed pairs in VGPRs ==========
    // pair p = 64k + lane  -> components (2p, 2p+1); one ds_read_b64 each.
    v2f C0[8], C1[8], C2[8], D0[8], D1[8], D2[8];
    #pragma unroll
    for (int k = 0; k < 8; k++) {
        const int p = (k << 6) + lane;
        C0[k] = COEF2[0][p];  C1[k] = COEF2[1][p];  C2[k] = COEF2[2][p];
        D0[k] = COEF2[3][p];  D1[k] = COEF2[4][p];  D2[k] = COEF2[5][p];
    }

    // ================= Phase 3: hot loop, 16 uniform samples ==============
    const int ls0 = wid * 16;
    const int sbu = __builtin_amdgcn_readfirstlane(blockIdx.x * 128 + ls0);

    #pragma unroll 2
    for (int s = 0; s < 16; ++s) {
        const float2 xy = ((const float2*)sample)[sbu + s];    // s_load
        const v2f Xv = {xy.x, xy.x}, Yv = {xy.y, xy.y};

        float s0 = 0.f, s1 = 0.f, s2 = 0.f, s3 = 0.f;
        #pragma unroll
        for (int k = 0; k < 8; k += 2) {
            // t = c0 + x*(c1 + d0*x + d1*y) + y*(c2 + d2*y)
            v2f i1a = pk_fma(D0[k],   Xv, C1[k]);
            v2f i1b = pk_fma(D0[k+1], Xv, C1[k+1]);
            i1a = pk_fma(D1[k],   Yv, i1a);
            i1b = pk_fma(D1[k+1], Yv, i1b);
            v2f i2a = pk_fma(D2[k],   Yv, C2[k]);
            v2f i2b = pk_fma(D2[k+1], Yv, C2[k+1]);
            v2f ta = pk_fma(i1a, Xv, C0[k]);
            v2f tb = pk_fma(i1b, Xv, C0[k+1]);
            ta = pk_fma(i2a, Yv, ta);
            tb = pk_fma(i2b, Yv, tb);
            s0 += fast_exp2(ta.x);
            s1 += fast_exp2(ta.y);
            s2 += fast_exp2(tb.x);
            s3 += fast_exp2(tb.y);
        }
        RED[ls0 + s][lane] = (s0 + s1) + (s2 + s3);
    }
    __syncthreads();

    // ---- stage 1: 4 partials per sample (2-way LDS access, free) ----
    {
        const int r = tid >> 2, c = tid & 3;
        const float* row = &RED[r][c * 16];
        float p = 0.f;
        #pragma unroll
        for (int i = 0; i < 16; i++) p += row[i];
        PART[r][c] = p;
    }
    __syncthreads();

    // ---- stage 2: finish 128 samples ----
    if (tid < 128) {
        const float st = (PART[tid][0] + PART[tid][1])
                       + (PART[tid][2] + PART[tid][3]);
        const int si = blockIdx.x * 128 + tid;
        float ll;
        if (st >= 1e-30f) {
            ll = LN2 * (Lmax + log2f(st));
        } else {
            // Rare underflow: re-anchored two-pass over all M from LDS COEF2.
            const float2 xy = ((const float2*)sample)[si];
            const float x = xy.x, y = xy.y;
            float m = -3e38f;
            for (int p = 0; p < 512; p++) {
                const v2f c0 = COEF2[0][p], c1 = COEF2[1][p], c2 = COEF2[2][p];
                const v2f d0 = COEF2[3][p], d1 = COEF2[4][p], d2 = COEF2[5][p];
                #pragma unroll
                for (int h = 0; h < 2; h++) {
                    float i1 = fmaf(d0[h], x, c1[h]);
                    i1 = fmaf(d1[h], y, i1);
                    float i2 = fmaf(d2[h], y, c2[h]);
                    float t = fmaf(i1, x, c0[h]);
                    t = fmaf(i2, y, t);
                    m = fmaxf(m, t);
                }
            }
            float ss = 0.f;
            for (int p = 0; p < 512; p++) {
                const v2f c0 = COEF2[0][p], c1 = COEF2[1][p], c2 = COEF2[2][p];
                const v2f d0 = COEF2[3][p], d1 = COEF2[4][p], d2 = COEF2[5][p];
                #pragma unroll
                for (int h = 0; h < 2; h++) {
                    float i1 = fmaf(d0[h], x, c1[h]);
                    i1 = fmaf(d1[h], y, i1);
                    float i2 = fmaf(d2[h], y, c2[h]);
                    float t = fmaf(i1, x, c0[h]);
                    t = fmaf(i2, y, t);
                    ss += fast_exp2(t - m);
                }
            }
            ll = LN2 * (Lmax + m + log2f(ss));
        }
        out[si] = ll;
    }
}

extern "C" void kernel_launch(void* const* d_in, const int* in_sizes, int n_in,
                              void* d_out, int out_size, void* d_ws, size_t ws_size,
                              hipStream_t stream) {
    const float* sample = (const float*)d_in[0];   // [N,2]
    const float* mu     = (const float*)d_in[1];   // [M,2]
    const float* A      = (const float*)d_in[2];   // [M,2,2]
    const float* w      = (const float*)d_in[3];   // [M,1]
    float* out = (float*)d_out;

    const int N = in_sizes[0] / 2;                 // 65536
    // M fixed at 1024 (register/LDS layouts sized statically).

    gm_fused<<<N / 128, 512, 0, stream>>>(sample, mu, A, w, out);
}